// Round 8
// baseline (680.780 us; speedup 1.0000x reference)
//
#include <hip/hip_runtime.h>
#include <hip/hip_bf16.h>
#include <math.h>

#define NH 4      // heads
#define OE 16     // OUT_E
#define ON 32     // OUT_N
#define INN 128   // IN_N
#define INE 32    // IN_E
#define HOE 64    // NH*OE
#define HON 128   // NH*ON

typedef __attribute__((ext_vector_type(8))) short bf16x8;
typedef __attribute__((ext_vector_type(4))) float f32x4;

__device__ __forceinline__ unsigned cvt_pk_bf16(float lo, float hi) {
    unsigned r;
    asm volatile("v_cvt_pk_bf16_f32 %0, %1, %2" : "=v"(r) : "v"(lo), "v"(hi));
    return r;
}

// sum over each 16-lane row via DPP row_ror (VALU only, no DS pipe)
__device__ __forceinline__ float rowsum16(float v) {
    int x;
    x = __builtin_amdgcn_update_dpp(0, __float_as_int(v), 0x128, 0xf, 0xf, true); // ror:8
    v += __int_as_float(x);
    x = __builtin_amdgcn_update_dpp(0, __float_as_int(v), 0x124, 0xf, 0xf, true); // ror:4
    v += __int_as_float(x);
    x = __builtin_amdgcn_update_dpp(0, __float_as_int(v), 0x122, 0xf, 0xf, true); // ror:2
    v += __int_as_float(x);
    x = __builtin_amdgcn_update_dpp(0, __float_as_int(v), 0x121, 0xf, 0xf, true); // ror:1
    v += __int_as_float(x);
    return v;
}

// ---------------- K0: zero int32 buffer ----------------
__global__ void k_zero_i32(int* __restrict__ p, int n) {
    int i = blockIdx.x * blockDim.x + threadIdx.x;
    int stride = gridDim.x * blockDim.x;
    for (; i < n; i += stride) p[i] = 0;
}

// ---------------- K0b: degree count ----------------
__global__ void k_count(const int* __restrict__ dst, int* __restrict__ count, int Ee) {
    int i = blockIdx.x * blockDim.x + threadIdx.x;
    int stride = gridDim.x * blockDim.x;
    for (; i < Ee; i += stride) atomicAdd(&count[dst[i]], 1);
}

// ---------------- K1: fused node GEMM via MFMA -------------------------------
// wave w: 0->fni, 1->fnj, 2->hproj even slots (cols 0..63), 3->hproj odd slots
// hproj stored INTERLEAVED: pos 2c = col c ; pos 2c+1 = col c+64
__launch_bounds__(256)
__global__ void k_node_gemm(const float* __restrict__ nf,
                            const float* __restrict__ Wni,
                            const float* __restrict__ Wnj,
                            const float* __restrict__ Wnode,
                            float* __restrict__ fni,
                            float* __restrict__ fnj,
                            float* __restrict__ hproj,
                            int Nn) {
    int tid = threadIdx.x;
    int lane = tid & 63;
    int w = tid >> 6;
    int m = lane & 15;
    int kq = lane >> 4;
    const float* W; float* out; int wstride, wcoff, ostride;
    int omul, oadd;
    if (w == 0)      { W = Wni;   wstride = 64;  wcoff = 0;  out = fni;   ostride = 64;  omul = 1; oadd = 0; }
    else if (w == 1) { W = Wnj;   wstride = 64;  wcoff = 0;  out = fnj;   ostride = 64;  omul = 1; oadd = 0; }
    else if (w == 2) { W = Wnode; wstride = 128; wcoff = 0;  out = hproj; ostride = 128; omul = 2; oadd = 0; }
    else             { W = Wnode; wstride = 128; wcoff = 64; out = hproj; ostride = 128; omul = 2; oadd = 1; }
    bf16x8 bv[4][4];
    #pragma unroll
    for (int k32 = 0; k32 < 4; k32++) {
        #pragma unroll
        for (int t = 0; t < 4; t++) {
            unsigned* bw = (unsigned*)&bv[k32][t];
            #pragma unroll
            for (int i = 0; i < 4; i++) {
                int k0 = k32 * 32 + kq * 8 + 2 * i;
                float lo = W[(size_t)k0 * wstride + wcoff + t * 16 + m];
                float hi = W[(size_t)(k0 + 1) * wstride + wcoff + t * 16 + m];
                bw[i] = cvt_pk_bf16(lo, hi);
            }
        }
    }
    int ngroups = (Nn + 15) >> 4;
    for (int g = blockIdx.x; g < ngroups; g += gridDim.x) {
        int r0 = g << 4;
        int ra = r0 + m; if (ra >= Nn) ra = Nn - 1;
        const float* ap = &nf[(size_t)ra * INN + kq * 8];
        bf16x8 av[4];
        #pragma unroll
        for (int k32 = 0; k32 < 4; k32++) {
            f32x4 a0 = *(const f32x4*)(ap + k32 * 32);
            f32x4 a1 = *(const f32x4*)(ap + k32 * 32 + 4);
            unsigned* aw = (unsigned*)&av[k32];
            aw[0] = cvt_pk_bf16(a0[0], a0[1]);
            aw[1] = cvt_pk_bf16(a0[2], a0[3]);
            aw[2] = cvt_pk_bf16(a1[0], a1[1]);
            aw[3] = cvt_pk_bf16(a1[2], a1[3]);
        }
        f32x4 c[4];
        #pragma unroll
        for (int t = 0; t < 4; t++) {
            c[t] = (f32x4){0.f, 0.f, 0.f, 0.f};
            #pragma unroll
            for (int k32 = 0; k32 < 4; k32++)
                c[t] = __builtin_amdgcn_mfma_f32_16x16x32_bf16(av[k32], bv[k32][t], c[t], 0, 0, 0);
        }
        #pragma unroll
        for (int t = 0; t < 4; t++) {
            #pragma unroll
            for (int j = 0; j < 4; j++) {
                int gr = r0 + kq * 4 + j;
                int col = t * 16 + m;
                if (gr < Nn) out[(size_t)gr * ostride + col * omul + oadd] = c[t][j];
            }
        }
    }
}

// ---------------- K2: edge pass — depth-2 pipelined --------------------------
#define MAXT 4
__launch_bounds__(256)
__global__ void k_edge(const float* __restrict__ efeats,
                       const int* __restrict__ src,
                       const int* __restrict__ dst,
                       const float* __restrict__ Wfij,   // [32][64]
                       const float* __restrict__ bias,   // [64]
                       const float* __restrict__ attn,   // [64]
                       const float* __restrict__ fni,
                       const float* __restrict__ fnj,
                       const int* __restrict__ offsets,  // [N+1]
                       int* __restrict__ cursor,         // [N]
                       int* __restrict__ eids,           // [E]
                       float* __restrict__ fout,         // [E,64]
                       float* __restrict__ exws,         // [E,4]
                       int Ee) {
    int tid = threadIdx.x;
    int lane = tid & 63;
    int m = lane & 15;
    int kq = lane >> 4;
    bf16x8 bv[4];
    #pragma unroll
    for (int t = 0; t < 4; t++) {
        unsigned* bw = (unsigned*)&bv[t];
        #pragma unroll
        for (int i = 0; i < 4; i++) {
            float lo = Wfij[(kq * 8 + 2 * i) * HOE + t * 16 + m];
            float hi = Wfij[(kq * 8 + 2 * i + 1) * HOE + t * 16 + m];
            bw[i] = cvt_pk_bf16(lo, hi);
        }
    }
    float bb[4], aa[4];
    #pragma unroll
    for (int t = 0; t < 4; t++) { bb[t] = bias[t * 16 + m]; aa[t] = attn[t * 16 + m]; }

    int wid = (blockIdx.x * 256 + tid) >> 6;
    int nw = gridDim.x * 4;
    int ntiles = (Ee + 15) >> 4;

    // preload meta for all (<=4) tiles of this wave
    int sj[MAXT][4], dj[MAXT][4];
    #pragma unroll
    for (int it = 0; it < MAXT; it++) {
        int T = wid + it * nw;
        #pragma unroll
        for (int j = 0; j < 4; j++) {
            int e = T * 16 + kq * 4 + j;
            int ec = (T < ntiles && e < Ee) ? e : 0;
            sj[it][j] = src[ec];
            dj[it][j] = dst[ec];
        }
    }

    f32x4 araw[2][2];
    float gni[2][4][4], gnj[2][4][4];

    // preamble: issue A + gathers for tile 0
    if (wid < ntiles) {
        int ea = wid * 16 + m; if (ea >= Ee) ea = Ee - 1;
        const float* ap = &efeats[(size_t)ea * INE + kq * 8];
        araw[0][0] = __builtin_nontemporal_load((const f32x4*)ap);
        araw[0][1] = __builtin_nontemporal_load((const f32x4*)(ap + 4));
        #pragma unroll
        for (int j = 0; j < 4; j++) {
            const float* pi = &fni[(size_t)sj[0][j] * HOE + m];
            const float* pj = &fnj[(size_t)dj[0][j] * HOE + m];
            #pragma unroll
            for (int t = 0; t < 4; t++) {
                gni[0][j][t] = pi[t * 16];
                gnj[0][j][t] = pj[t * 16];
            }
        }
    }

    #pragma unroll
    for (int it = 0; it < MAXT; it++) {
        int T = wid + it * nw;
        if (T < ntiles) {
            const int cur = it & 1, nxt = cur ^ 1;
            // issue next tile's A + gathers
            if (it + 1 < MAXT) {
                int Tn = T + nw;
                if (Tn < ntiles) {
                    int ea = Tn * 16 + m; if (ea >= Ee) ea = Ee - 1;
                    const float* ap = &efeats[(size_t)ea * INE + kq * 8];
                    araw[nxt][0] = __builtin_nontemporal_load((const f32x4*)ap);
                    araw[nxt][1] = __builtin_nontemporal_load((const f32x4*)(ap + 4));
                    const int itn = (it + 1 < MAXT) ? it + 1 : 0;
                    #pragma unroll
                    for (int j = 0; j < 4; j++) {
                        const float* pi = &fni[(size_t)sj[itn][j] * HOE + m];
                        const float* pj = &fnj[(size_t)dj[itn][j] * HOE + m];
                        #pragma unroll
                        for (int t = 0; t < 4; t++) {
                            gni[nxt][j][t] = pi[t * 16];
                            gnj[nxt][j][t] = pj[t * 16];
                        }
                    }
                }
            }
            // MFMA for current tile
            bf16x8 av;
            {
                unsigned* aw = (unsigned*)&av;
                aw[0] = cvt_pk_bf16(araw[cur][0][0], araw[cur][0][1]);
                aw[1] = cvt_pk_bf16(araw[cur][0][2], araw[cur][0][3]);
                aw[2] = cvt_pk_bf16(araw[cur][1][0], araw[cur][1][1]);
                aw[3] = cvt_pk_bf16(araw[cur][1][2], araw[cur][1][3]);
            }
            f32x4 c[4];
            #pragma unroll
            for (int t = 0; t < 4; t++) {
                c[t] = __builtin_amdgcn_mfma_f32_16x16x32_bf16(av, bv[t], (f32x4){0.f,0.f,0.f,0.f}, 0, 0, 0);
            }
            // epilogue for current tile
            int e0 = T * 16;
            #pragma unroll
            for (int j = 0; j < 4; j++) {
                int eq = e0 + kq * 4 + j;
                bool ok = eq < Ee;
                #pragma unroll
                for (int t = 0; t < 4; t++) {
                    int col = t * 16 + m;
                    float fv = c[t][j] + gni[cur][j][t] + gnj[cur][j][t] + bb[t];
                    fv = fv > 0.f ? fv : 0.01f * fv;          // leaky relu
                    if (ok) __builtin_nontemporal_store(fv, &fout[(size_t)eq * HOE + col]);
                    float pl = rowsum16(fv * aa[t]);
                    if (ok && m == 0) exws[(size_t)eq * NH + t] = __expf(pl);
                }
                if (ok && m == 0) {
                    int dd = dj[it][j];
                    int p = atomicAdd(&cursor[dd], 1);
                    eids[offsets[dd] + p] = eq;
                }
            }
        }
    }
}

// ---------------- K3a: per-chunk exclusive scan (chunks of 256) --------------
__global__ void k_scan_chunks(const int* __restrict__ count,
                              int* __restrict__ chunkscan,
                              int* __restrict__ chunktot, int n) {
    __shared__ int tmp[256];
    int t = threadIdx.x;
    int i = blockIdx.x * 256 + t;
    int v = (i < n) ? count[i] : 0;
    tmp[t] = v;
    __syncthreads();
    for (int o = 1; o < 256; o <<= 1) {
        int x = (t >= o) ? tmp[t - o] : 0;
        __syncthreads();
        tmp[t] += x;
        __syncthreads();
    }
    if (i < n) chunkscan[i] = tmp[t] - v;
    if (t == 255) chunktot[blockIdx.x] = tmp[t];
}

// ---------------- K3b: scan chunk totals (single block) ----------------------
__global__ void k_scan_tot(const int* __restrict__ tot, int* __restrict__ base, int nc) {
    __shared__ int tmp[1024];
    int t = threadIdx.x;
    int v = (t < nc) ? tot[t] : 0;
    tmp[t] = v;
    __syncthreads();
    for (int o = 1; o < 1024; o <<= 1) {
        int x = (t >= o) ? tmp[t - o] : 0;
        __syncthreads();
        tmp[t] += x;
        __syncthreads();
    }
    if (t < nc) base[t] = tmp[t] - v;
}

// ---------------- K3c: final offsets ----------------------------------------
__global__ void k_offsets(const int* __restrict__ chunkscan,
                          const int* __restrict__ chunkbase,
                          int* __restrict__ offsets, int Nn, int Ee) {
    int i = blockIdx.x * blockDim.x + threadIdx.x;
    if (i < Nn) offsets[i] = chunkscan[i] + chunkbase[i >> 8];
    if (i == 0) offsets[Nn] = Ee;
}

// ---------------- K5: node-centric softmax + aggregation ---------------------
__launch_bounds__(256)
__global__ void k_node_out(const int* __restrict__ offsets,
                           const int* __restrict__ eids,
                           const int* __restrict__ srcv,
                           const float* __restrict__ exws,    // [E,4]
                           const float* __restrict__ hproj2,  // [N,128] interleaved
                           float* __restrict__ hout,          // [N,128]
                           int Nn) {
    int lane = threadIdx.x & 63;
    int n = (blockIdx.x * 256 + threadIdx.x) >> 6;
    if (n >= Nn) return;
    int o0 = offsets[n], o1 = offsets[n + 1];
    int hi = lane >> 5;
    float s0 = 0.f, s1 = 0.f, s2 = 0.f, s3 = 0.f;
    float a0 = 0.f, a1 = 0.f;
    for (int i0 = o0; i0 < o1; i0 += 64) {
        int nb = min(64, o1 - i0);
        int ve = 0, vs = 0;
        if (lane < nb) {
            ve = eids[i0 + lane];
            vs = srcv[ve];
        }
        for (int j0 = 0; j0 < nb; j0 += 4) {
            int cnt = nb - j0;
            float4 xx[4]; float2 hp[4];
            #pragma unroll
            for (int u = 0; u < 4; u++) {
                int jj = j0 + ((u < cnt) ? u : cnt - 1);
                int e = __builtin_amdgcn_readlane(ve, jj);
                int s = __builtin_amdgcn_readlane(vs, jj);
                xx[u] = *(const float4*)&exws[(size_t)e * NH];
                hp[u] = *(const float2*)&hproj2[(size_t)s * HON + lane * 2];
            }
            #pragma unroll
            for (int u = 0; u < 4; u++) {
                float4 x = xx[u];
                if (u >= cnt) x = make_float4(0.f, 0.f, 0.f, 0.f);
                s0 += x.x; s1 += x.y; s2 += x.z; s3 += x.w;
                float exl = (hi == 0) ? x.x : x.y;
                float exh = (hi == 0) ? x.z : x.w;
                a0 += hp[u].x * exl;
                a1 += hp[u].y * exh;
            }
        }
    }
    float r0 = s0 > 0.f ? 1.f / s0 : 0.f;
    float r1 = s1 > 0.f ? 1.f / s1 : 0.f;
    float r2 = s2 > 0.f ? 1.f / s2 : 0.f;
    float r3 = s3 > 0.f ? 1.f / s3 : 0.f;
    float rlo = (hi == 0) ? r0 : r1;
    float rhi = (hi == 0) ? r2 : r3;
    __builtin_nontemporal_store(a0 * rlo, &hout[(size_t)n * HON + lane]);
    __builtin_nontemporal_store(a1 * rhi, &hout[(size_t)n * HON + 64 + lane]);
}

// ---------------- launcher ----------------
extern "C" void kernel_launch(void* const* d_in, const int* in_sizes, int n_in,
                              void* d_out, int out_size, void* d_ws, size_t ws_size,
                              hipStream_t stream) {
    const float* n_feats = (const float*)d_in[0];
    const float* e_feats = (const float*)d_in[1];
    const int*   src     = (const int*)d_in[2];
    const int*   dst     = (const int*)d_in[3];
    const float* W_ni    = (const float*)d_in[4];
    const float* W_nj    = (const float*)d_in[5];
    const float* W_fij   = (const float*)d_in[6];
    const float* bias_e  = (const float*)d_in[7];
    const float* attn    = (const float*)d_in[8];
    const float* W_node  = (const float*)d_in[9];

    const int Nn = in_sizes[0] / INN;
    const int Ee = in_sizes[2];

    float* hout = (float*)d_out;                       // [N,128]
    float* fout = (float*)d_out + (size_t)Nn * HON;    // [E,64]

    char* ws = (char*)d_ws;
    size_t off = 0;
    auto alloc = [&](size_t bytes) {
        size_t o = off;
        off = (off + bytes + 255) & ~(size_t)255;
        return o;
    };
    size_t o_fni   = alloc((size_t)Nn * HOE * 4);
    size_t o_fnj   = alloc((size_t)Nn * HOE * 4);
    size_t o_hproj = alloc((size_t)Nn * HON * 4);
    size_t o_exws  = alloc((size_t)Ee * NH * 4);
    size_t o_eids  = alloc((size_t)Ee * 4);
    size_t o_cnt2  = alloc((size_t)2 * Nn * 4);        // count | cursor
    size_t o_offs  = alloc((size_t)(Nn + 1) * 4);
    size_t o_cscan = alloc((size_t)Nn * 4);
    size_t o_cbase = alloc((size_t)1024 * 4);
    (void)ws_size;

    float* fni   = (float*)(ws + o_fni);
    float* fnj   = (float*)(ws + o_fnj);
    float* hproj = (float*)(ws + o_hproj);
    float* exws  = (float*)(ws + o_exws);
    int* eids    = (int*)(ws + o_eids);
    int* cnt2    = (int*)(ws + o_cnt2);
    int* count   = cnt2;
    int* cursor  = cnt2 + Nn;
    int* offsets = (int*)(ws + o_offs);
    int* cscan   = (int*)(ws + o_cscan);
    int* cbase   = (int*)(ws + o_cbase);

    int nchunks = (Nn + 255) / 256;
    int ntiles = (Ee + 15) >> 4;
    int nblk_edge = (ntiles + 15) / 16;   // each wave gets <= MAXT(=4) tiles

    k_zero_i32<<<(2 * Nn + 255) / 256, 256, 0, stream>>>(cnt2, 2 * Nn);

    k_count<<<2048, 256, 0, stream>>>(dst, count, Ee);

    k_node_gemm<<<1024, 256, 0, stream>>>(
        n_feats, W_ni, W_nj, W_node, fni, fnj, hproj, Nn);

    k_scan_chunks<<<nchunks, 256, 0, stream>>>(count, cscan, cbase, Nn);
    k_scan_tot<<<1, 1024, 0, stream>>>(cbase, cbase, nchunks);
    k_offsets<<<(Nn + 255) / 256, 256, 0, stream>>>(cscan, cbase, offsets, Nn, Ee);

    k_edge<<<nblk_edge, 256, 0, stream>>>(
        e_feats, src, dst, W_fij, bias_e, attn, fni, fnj,
        offsets, cursor, eids, fout, exws, Ee);

    k_node_out<<<(Nn + 3) / 4, 256, 0, stream>>>(
        offsets, eids, src, exws, hproj, hout, Nn);
}

// Round 9
// 654.096 us; speedup vs baseline: 1.0408x; 1.0408x over previous
//
#include <hip/hip_runtime.h>
#include <hip/hip_bf16.h>
#include <math.h>

#define NH 4      // heads
#define OE 16     // OUT_E
#define ON 32     // OUT_N
#define INN 128   // IN_N
#define INE 32    // IN_E
#define HOE 64    // NH*OE
#define HON 128   // NH*ON

typedef __attribute__((ext_vector_type(8))) short bf16x8;
typedef __attribute__((ext_vector_type(4))) float f32x4;

__device__ __forceinline__ unsigned cvt_pk_bf16(float lo, float hi) {
    unsigned r;
    asm volatile("v_cvt_pk_bf16_f32 %0, %1, %2" : "=v"(r) : "v"(lo), "v"(hi));
    return r;
}

// sum over each 16-lane row via DPP row_ror (VALU only, no DS pipe)
__device__ __forceinline__ float rowsum16(float v) {
    int x;
    x = __builtin_amdgcn_update_dpp(0, __float_as_int(v), 0x128, 0xf, 0xf, true); // ror:8
    v += __int_as_float(x);
    x = __builtin_amdgcn_update_dpp(0, __float_as_int(v), 0x124, 0xf, 0xf, true); // ror:4
    v += __int_as_float(x);
    x = __builtin_amdgcn_update_dpp(0, __float_as_int(v), 0x122, 0xf, 0xf, true); // ror:2
    v += __int_as_float(x);
    x = __builtin_amdgcn_update_dpp(0, __float_as_int(v), 0x121, 0xf, 0xf, true); // ror:1
    v += __int_as_float(x);
    return v;
}

// ---------------- K0: zero int32 buffer ----------------
__global__ void k_zero_i32(int* __restrict__ p, int n) {
    int i = blockIdx.x * blockDim.x + threadIdx.x;
    int stride = gridDim.x * blockDim.x;
    for (; i < n; i += stride) p[i] = 0;
}

// ---------------- K0b: degree count ----------------
__global__ void k_count(const int* __restrict__ dst, int* __restrict__ count, int Ee) {
    int i = blockIdx.x * blockDim.x + threadIdx.x;
    int stride = gridDim.x * blockDim.x;
    for (; i < Ee; i += stride) atomicAdd(&count[dst[i]], 1);
}

// ---------------- K1: fused node GEMM via MFMA -------------------------------
// wave w: 0->fni, 1->fnj, 2->hproj even slots, 3->hproj odd slots
// hproj stored INTERLEAVED: pos 2c = col c ; pos 2c+1 = col c+64
__launch_bounds__(256)
__global__ void k_node_gemm(const float* __restrict__ nf,
                            const float* __restrict__ Wni,
                            const float* __restrict__ Wnj,
                            const float* __restrict__ Wnode,
                            float* __restrict__ fni,
                            float* __restrict__ fnj,
                            float* __restrict__ hproj,
                            int Nn) {
    int tid = threadIdx.x;
    int lane = tid & 63;
    int w = tid >> 6;
    int m = lane & 15;
    int kq = lane >> 4;
    const float* W; float* out; int wstride, wcoff, ostride;
    int omul, oadd;
    if (w == 0)      { W = Wni;   wstride = 64;  wcoff = 0;  out = fni;   ostride = 64;  omul = 1; oadd = 0; }
    else if (w == 1) { W = Wnj;   wstride = 64;  wcoff = 0;  out = fnj;   ostride = 64;  omul = 1; oadd = 0; }
    else if (w == 2) { W = Wnode; wstride = 128; wcoff = 0;  out = hproj; ostride = 128; omul = 2; oadd = 0; }
    else             { W = Wnode; wstride = 128; wcoff = 64; out = hproj; ostride = 128; omul = 2; oadd = 1; }
    bf16x8 bv[4][4];
    #pragma unroll
    for (int k32 = 0; k32 < 4; k32++) {
        #pragma unroll
        for (int t = 0; t < 4; t++) {
            unsigned* bw = (unsigned*)&bv[k32][t];
            #pragma unroll
            for (int i = 0; i < 4; i++) {
                int k0 = k32 * 32 + kq * 8 + 2 * i;
                float lo = W[(size_t)k0 * wstride + wcoff + t * 16 + m];
                float hi = W[(size_t)(k0 + 1) * wstride + wcoff + t * 16 + m];
                bw[i] = cvt_pk_bf16(lo, hi);
            }
        }
    }
    int ngroups = (Nn + 15) >> 4;
    for (int g = blockIdx.x; g < ngroups; g += gridDim.x) {
        int r0 = g << 4;
        int ra = r0 + m; if (ra >= Nn) ra = Nn - 1;
        const float* ap = &nf[(size_t)ra * INN + kq * 8];
        bf16x8 av[4];
        #pragma unroll
        for (int k32 = 0; k32 < 4; k32++) {
            f32x4 a0 = *(const f32x4*)(ap + k32 * 32);
            f32x4 a1 = *(const f32x4*)(ap + k32 * 32 + 4);
            unsigned* aw = (unsigned*)&av[k32];
            aw[0] = cvt_pk_bf16(a0[0], a0[1]);
            aw[1] = cvt_pk_bf16(a0[2], a0[3]);
            aw[2] = cvt_pk_bf16(a1[0], a1[1]);
            aw[3] = cvt_pk_bf16(a1[2], a1[3]);
        }
        f32x4 c[4];
        #pragma unroll
        for (int t = 0; t < 4; t++) {
            c[t] = (f32x4){0.f, 0.f, 0.f, 0.f};
            #pragma unroll
            for (int k32 = 0; k32 < 4; k32++)
                c[t] = __builtin_amdgcn_mfma_f32_16x16x32_bf16(av[k32], bv[k32][t], c[t], 0, 0, 0);
        }
        #pragma unroll
        for (int t = 0; t < 4; t++) {
            #pragma unroll
            for (int j = 0; j < 4; j++) {
                int gr = r0 + kq * 4 + j;
                int col = t * 16 + m;
                if (gr < Nn) out[(size_t)gr * ostride + col * omul + oadd] = c[t][j];
            }
        }
    }
}

// ---------------- K3a: per-chunk exclusive scan (chunks of 256) --------------
__global__ void k_scan_chunks(const int* __restrict__ count,
                              int* __restrict__ chunkscan,
                              int* __restrict__ chunktot, int n) {
    __shared__ int tmp[256];
    int t = threadIdx.x;
    int i = blockIdx.x * 256 + t;
    int v = (i < n) ? count[i] : 0;
    tmp[t] = v;
    __syncthreads();
    for (int o = 1; o < 256; o <<= 1) {
        int x = (t >= o) ? tmp[t - o] : 0;
        __syncthreads();
        tmp[t] += x;
        __syncthreads();
    }
    if (i < n) chunkscan[i] = tmp[t] - v;
    if (t == 255) chunktot[blockIdx.x] = tmp[t];
}

// ---------------- K3b: scan chunk totals (single block) ----------------------
__global__ void k_scan_tot(const int* __restrict__ tot, int* __restrict__ base, int nc) {
    __shared__ int tmp[1024];
    int t = threadIdx.x;
    int v = (t < nc) ? tot[t] : 0;
    tmp[t] = v;
    __syncthreads();
    for (int o = 1; o < 1024; o <<= 1) {
        int x = (t >= o) ? tmp[t - o] : 0;
        __syncthreads();
        tmp[t] += x;
        __syncthreads();
    }
    if (t < nc) base[t] = tmp[t] - v;
}

// ---------------- K3c: final offsets ----------------------------------------
__global__ void k_offsets(const int* __restrict__ chunkscan,
                          const int* __restrict__ chunkbase,
                          int* __restrict__ offsets, int Nn, int Ee) {
    int i = blockIdx.x * blockDim.x + threadIdx.x;
    if (i < Nn) offsets[i] = chunkscan[i] + chunkbase[i >> 8];
    if (i == 0) offsets[Nn] = Ee;
}

// ---------------- K4: fill CSR edge lists ------------------------------------
__global__ void k_fill(const int* __restrict__ dst,
                       const int* __restrict__ offsets,
                       int* __restrict__ cursor,
                       int* __restrict__ eids, int Ee) {
    int i = blockIdx.x * blockDim.x + threadIdx.x;
    int stride = gridDim.x * blockDim.x;
    for (; i < Ee; i += stride) {
        int d = dst[i];
        int p = atomicAdd(&cursor[d], 1);
        eids[offsets[d] + p] = i;
    }
}

// ---------------- K2: edge pass in CSR (dst-grouped) order -------------------
// Tile = 16 CSR positions. fnj[d] gathers hit L1 (runs share d); src/dst/eids
// are L2-resident. Outputs exws & src PERMUTED (sequential streams).
__launch_bounds__(256)
__global__ void k_edge(const float* __restrict__ efeats,
                       const int* __restrict__ src,
                       const int* __restrict__ dst,
                       const float* __restrict__ Wfij,   // [32][64]
                       const float* __restrict__ bias,   // [64]
                       const float* __restrict__ attn,   // [64]
                       const float* __restrict__ fni,
                       const float* __restrict__ fnj,
                       const int* __restrict__ eids,     // [E] CSR order
                       float* __restrict__ fout,         // [E,64] original order
                       float* __restrict__ exwsp,        // [E,4] CSR order
                       int* __restrict__ srcp,           // [E]   CSR order
                       int Ee) {
    int tid = threadIdx.x;
    int lane = tid & 63;
    int m = lane & 15;
    int kq = lane >> 4;
    bf16x8 bv[4];
    #pragma unroll
    for (int t = 0; t < 4; t++) {
        unsigned* bw = (unsigned*)&bv[t];
        #pragma unroll
        for (int i = 0; i < 4; i++) {
            float lo = Wfij[(kq * 8 + 2 * i) * HOE + t * 16 + m];
            float hi = Wfij[(kq * 8 + 2 * i + 1) * HOE + t * 16 + m];
            bw[i] = cvt_pk_bf16(lo, hi);
        }
    }
    float bb[4], aa[4];
    #pragma unroll
    for (int t = 0; t < 4; t++) { bb[t] = bias[t * 16 + m]; aa[t] = attn[t * 16 + m]; }

    int wid = (blockIdx.x * 256 + tid) >> 6;
    int nw = (gridDim.x * 256) >> 6;
    int ntiles = (Ee + 15) >> 4;
    for (int T = wid; T < ntiles; T += nw) {
        int i0 = T << 4;
        // A row for this lane (eids line is L1-shared across the wave)
        int ia = i0 + m;
        int ra = eids[(ia < Ee) ? ia : (Ee - 1)];
        const float* ap = &efeats[(size_t)ra * INE + kq * 8];
        f32x4 a0 = *(const f32x4*)ap;
        f32x4 a1 = *(const f32x4*)(ap + 4);
        // epilogue meta: 4 positions per lane-group
        int eq[4], sj[4], dj[4]; bool ok[4];
        #pragma unroll
        for (int j = 0; j < 4; j++) {
            int pos = i0 + kq * 4 + j;
            ok[j] = pos < Ee;
            int pc = ok[j] ? pos : (Ee - 1);
            eq[j] = eids[pc];
            sj[j] = src[eq[j]];          // L2-resident gather
            dj[j] = dst[eq[j]];          // L2-resident gather
        }
        // gather clause: fni random (L2/L3), fnj same-d runs (L1)
        float gni[4][4], gnj[4][4];
        #pragma unroll
        for (int j = 0; j < 4; j++) {
            const float* pi = &fni[(size_t)sj[j] * HOE + m];
            const float* pj = &fnj[(size_t)dj[j] * HOE + m];
            #pragma unroll
            for (int t = 0; t < 4; t++) {
                gni[j][t] = pi[t * 16];
                gnj[j][t] = pj[t * 16];
            }
        }
        // cvt + MFMA while gathers land
        bf16x8 av;
        {
            unsigned* aw = (unsigned*)&av;
            aw[0] = cvt_pk_bf16(a0[0], a0[1]);
            aw[1] = cvt_pk_bf16(a0[2], a0[3]);
            aw[2] = cvt_pk_bf16(a1[0], a1[1]);
            aw[3] = cvt_pk_bf16(a1[2], a1[3]);
        }
        f32x4 c[4];
        #pragma unroll
        for (int t = 0; t < 4; t++) {
            c[t] = __builtin_amdgcn_mfma_f32_16x16x32_bf16(av, bv[t], (f32x4){0.f,0.f,0.f,0.f}, 0, 0, 0);
        }
        // epilogue
        #pragma unroll
        for (int j = 0; j < 4; j++) {
            int pos = i0 + kq * 4 + j;
            float pl[4];
            #pragma unroll
            for (int t = 0; t < 4; t++) {
                int col = t * 16 + m;
                float fv = c[t][j] + gni[j][t] + gnj[j][t] + bb[t];
                fv = fv > 0.f ? fv : 0.01f * fv;          // leaky relu
                if (ok[j]) fout[(size_t)eq[j] * HOE + col] = fv;
                pl[t] = rowsum16(fv * aa[t]);
            }
            if (ok[j] && m == 0) {
                float4 ex = make_float4(__expf(pl[0]), __expf(pl[1]),
                                        __expf(pl[2]), __expf(pl[3]));
                *(float4*)&exwsp[(size_t)pos * NH] = ex;   // sequential stream
                srcp[pos] = sj[j];                          // sequential stream
            }
        }
    }
}

// ---------------- K5: node-centric softmax + aggregation ---------------------
// exwsp/srcp are CSR-sequential: coalesced/uniform loads; only hproj gathers.
__launch_bounds__(256)
__global__ void k_node_out(const int* __restrict__ offsets,
                           const int* __restrict__ srcp,
                           const float* __restrict__ exwsp,   // [E,4] CSR order
                           const float* __restrict__ hproj2,  // [N,128] interleaved
                           float* __restrict__ hout,          // [N,128]
                           int Nn) {
    int lane = threadIdx.x & 63;
    int n = (blockIdx.x * 256 + threadIdx.x) >> 6;
    if (n >= Nn) return;
    int o0 = offsets[n], o1 = offsets[n + 1];
    int hi = lane >> 5;
    float s0 = 0.f, s1 = 0.f, s2 = 0.f, s3 = 0.f;
    float a0 = 0.f, a1 = 0.f;
    for (int i0 = o0; i0 < o1; i0 += 64) {
        int nb = min(64, o1 - i0);
        int vs = 0;
        if (lane < nb) vs = srcp[i0 + lane];               // coalesced
        for (int j0 = 0; j0 < nb; j0 += 4) {
            int cnt = nb - j0;
            float4 xx[4]; float2 hp[4];
            #pragma unroll
            for (int u = 0; u < 4; u++) {
                int jj = j0 + ((u < cnt) ? u : cnt - 1);
                int s = __builtin_amdgcn_readlane(vs, jj);
                xx[u] = *(const float4*)&exwsp[(size_t)(i0 + jj) * NH];  // uniform addr
                hp[u] = *(const float2*)&hproj2[(size_t)s * HON + lane * 2];
            }
            #pragma unroll
            for (int u = 0; u < 4; u++) {
                float4 x = xx[u];
                if (u >= cnt) x = make_float4(0.f, 0.f, 0.f, 0.f);
                s0 += x.x; s1 += x.y; s2 += x.z; s3 += x.w;
                float exl = (hi == 0) ? x.x : x.y;
                float exh = (hi == 0) ? x.z : x.w;
                a0 += hp[u].x * exl;
                a1 += hp[u].y * exh;
            }
        }
    }
    float r0 = s0 > 0.f ? 1.f / s0 : 0.f;
    float r1 = s1 > 0.f ? 1.f / s1 : 0.f;
    float r2 = s2 > 0.f ? 1.f / s2 : 0.f;
    float r3 = s3 > 0.f ? 1.f / s3 : 0.f;
    float rlo = (hi == 0) ? r0 : r1;
    float rhi = (hi == 0) ? r2 : r3;
    hout[(size_t)n * HON + lane] = a0 * rlo;
    hout[(size_t)n * HON + 64 + lane] = a1 * rhi;
}

// ---------------- launcher ----------------
extern "C" void kernel_launch(void* const* d_in, const int* in_sizes, int n_in,
                              void* d_out, int out_size, void* d_ws, size_t ws_size,
                              hipStream_t stream) {
    const float* n_feats = (const float*)d_in[0];
    const float* e_feats = (const float*)d_in[1];
    const int*   src     = (const int*)d_in[2];
    const int*   dst     = (const int*)d_in[3];
    const float* W_ni    = (const float*)d_in[4];
    const float* W_nj    = (const float*)d_in[5];
    const float* W_fij   = (const float*)d_in[6];
    const float* bias_e  = (const float*)d_in[7];
    const float* attn    = (const float*)d_in[8];
    const float* W_node  = (const float*)d_in[9];

    const int Nn = in_sizes[0] / INN;
    const int Ee = in_sizes[2];

    float* hout = (float*)d_out;                       // [N,128]
    float* fout = (float*)d_out + (size_t)Nn * HON;    // [E,64]

    char* ws = (char*)d_ws;
    size_t off = 0;
    auto alloc = [&](size_t bytes) {
        size_t o = off;
        off = (off + bytes + 255) & ~(size_t)255;
        return o;
    };
    size_t o_fni   = alloc((size_t)Nn * HOE * 4);
    size_t o_fnj   = alloc((size_t)Nn * HOE * 4);
    size_t o_hproj = alloc((size_t)Nn * HON * 4);
    size_t o_exws  = alloc((size_t)Ee * NH * 4);
    size_t o_eids  = alloc((size_t)Ee * 4);
    size_t o_srcp  = alloc((size_t)Ee * 4);
    size_t o_cnt2  = alloc((size_t)2 * Nn * 4);        // count | cursor
    size_t o_offs  = alloc((size_t)(Nn + 1) * 4);
    size_t o_cscan = alloc((size_t)Nn * 4);
    size_t o_cbase = alloc((size_t)1024 * 4);
    (void)ws_size;

    float* fni   = (float*)(ws + o_fni);
    float* fnj   = (float*)(ws + o_fnj);
    float* hproj = (float*)(ws + o_hproj);
    float* exwsp = (float*)(ws + o_exws);
    int* eids    = (int*)(ws + o_eids);
    int* srcp    = (int*)(ws + o_srcp);
    int* cnt2    = (int*)(ws + o_cnt2);
    int* count   = cnt2;
    int* cursor  = cnt2 + Nn;
    int* offsets = (int*)(ws + o_offs);
    int* cscan   = (int*)(ws + o_cscan);
    int* cbase   = (int*)(ws + o_cbase);

    int nchunks = (Nn + 255) / 256;

    k_zero_i32<<<(2 * Nn + 255) / 256, 256, 0, stream>>>(cnt2, 2 * Nn);

    k_count<<<2048, 256, 0, stream>>>(dst, count, Ee);

    k_node_gemm<<<1024, 256, 0, stream>>>(
        n_feats, W_ni, W_nj, W_node, fni, fnj, hproj, Nn);

    k_scan_chunks<<<nchunks, 256, 0, stream>>>(count, cscan, cbase, Nn);
    k_scan_tot<<<1, 1024, 0, stream>>>(cbase, cbase, nchunks);
    k_offsets<<<(Nn + 255) / 256, 256, 0, stream>>>(cscan, cbase, offsets, Nn, Ee);

    k_fill<<<4096, 256, 0, stream>>>(dst, offsets, cursor, eids, Ee);

    k_edge<<<8192, 256, 0, stream>>>(
        e_feats, src, dst, W_fij, bias_e, attn, fni, fnj,
        eids, fout, exwsp, srcp, Ee);

    k_node_out<<<(Nn + 3) / 4, 256, 0, stream>>>(
        offsets, srcp, exwsp, hproj, hout, Nn);
}

// Round 10
// 607.742 us; speedup vs baseline: 1.1202x; 1.0763x over previous
//
#include <hip/hip_runtime.h>
#include <hip/hip_bf16.h>
#include <math.h>

#define NH 4      // heads
#define OE 16     // OUT_E
#define ON 32     // OUT_N
#define INN 128   // IN_N
#define INE 32    // IN_E
#define HOE 64    // NH*OE
#define HON 128   // NH*ON

typedef __attribute__((ext_vector_type(8))) short bf16x8;
typedef __attribute__((ext_vector_type(4))) float f32x4;

__device__ __forceinline__ unsigned cvt_pk_bf16(float lo, float hi) {
    unsigned r;
    asm volatile("v_cvt_pk_bf16_f32 %0, %1, %2" : "=v"(r) : "v"(lo), "v"(hi));
    return r;
}

__device__ __forceinline__ unsigned short f32_to_bf16_bits(float x) {
    unsigned u = __float_as_uint(x);
    unsigned r = (u + 0x7fff + ((u >> 16) & 1)) >> 16;   // RNE
    return (unsigned short)r;
}

// sum over each 16-lane row via DPP row_ror (VALU only, no DS pipe)
__device__ __forceinline__ float rowsum16(float v) {
    int x;
    x = __builtin_amdgcn_update_dpp(0, __float_as_int(v), 0x128, 0xf, 0xf, true); // ror:8
    v += __int_as_float(x);
    x = __builtin_amdgcn_update_dpp(0, __float_as_int(v), 0x124, 0xf, 0xf, true); // ror:4
    v += __int_as_float(x);
    x = __builtin_amdgcn_update_dpp(0, __float_as_int(v), 0x122, 0xf, 0xf, true); // ror:2
    v += __int_as_float(x);
    x = __builtin_amdgcn_update_dpp(0, __float_as_int(v), 0x121, 0xf, 0xf, true); // ror:1
    v += __int_as_float(x);
    return v;
}

// ---------------- K0: zero int32 buffer ----------------
__global__ void k_zero_i32(int* __restrict__ p, int n) {
    int i = blockIdx.x * blockDim.x + threadIdx.x;
    int stride = gridDim.x * blockDim.x;
    for (; i < n; i += stride) p[i] = 0;
}

// ---------------- K0b: degree count ----------------
__global__ void k_count(const int* __restrict__ dst, int* __restrict__ count, int Ee) {
    int i = blockIdx.x * blockDim.x + threadIdx.x;
    int stride = gridDim.x * blockDim.x;
    for (; i < Ee; i += stride) atomicAdd(&count[dst[i]], 1);
}

// ---------------- K1: fused node GEMM via MFMA -------------------------------
// wave 0->fni (f32), 1->fnj (f32), 2->hproj lo bf16, 3->hproj hi bf16
// hproj layout: ushort[row][128], idx 2c = col c (bf16), 2c+1 = col c+64 (bf16)
__launch_bounds__(256)
__global__ void k_node_gemm(const float* __restrict__ nf,
                            const float* __restrict__ Wni,
                            const float* __restrict__ Wnj,
                            const float* __restrict__ Wnode,
                            float* __restrict__ fni,
                            float* __restrict__ fnj,
                            unsigned short* __restrict__ hproj,
                            int Nn) {
    int tid = threadIdx.x;
    int lane = tid & 63;
    int w = tid >> 6;
    int m = lane & 15;
    int kq = lane >> 4;
    const float* W; int wstride, wcoff;
    if (w == 0)      { W = Wni;   wstride = 64;  wcoff = 0;  }
    else if (w == 1) { W = Wnj;   wstride = 64;  wcoff = 0;  }
    else if (w == 2) { W = Wnode; wstride = 128; wcoff = 0;  }
    else             { W = Wnode; wstride = 128; wcoff = 64; }
    float* outf = (w == 0) ? fni : fnj;
    int hsel = (w == 3);
    bf16x8 bv[4][4];
    #pragma unroll
    for (int k32 = 0; k32 < 4; k32++) {
        #pragma unroll
        for (int t = 0; t < 4; t++) {
            unsigned* bw = (unsigned*)&bv[k32][t];
            #pragma unroll
            for (int i = 0; i < 4; i++) {
                int k0 = k32 * 32 + kq * 8 + 2 * i;
                float lo = W[(size_t)k0 * wstride + wcoff + t * 16 + m];
                float hi = W[(size_t)(k0 + 1) * wstride + wcoff + t * 16 + m];
                bw[i] = cvt_pk_bf16(lo, hi);
            }
        }
    }
    int ngroups = (Nn + 15) >> 4;
    for (int g = blockIdx.x; g < ngroups; g += gridDim.x) {
        int r0 = g << 4;
        int ra = r0 + m; if (ra >= Nn) ra = Nn - 1;
        const float* ap = &nf[(size_t)ra * INN + kq * 8];
        bf16x8 av[4];
        #pragma unroll
        for (int k32 = 0; k32 < 4; k32++) {
            f32x4 a0 = *(const f32x4*)(ap + k32 * 32);
            f32x4 a1 = *(const f32x4*)(ap + k32 * 32 + 4);
            unsigned* aw = (unsigned*)&av[k32];
            aw[0] = cvt_pk_bf16(a0[0], a0[1]);
            aw[1] = cvt_pk_bf16(a0[2], a0[3]);
            aw[2] = cvt_pk_bf16(a1[0], a1[1]);
            aw[3] = cvt_pk_bf16(a1[2], a1[3]);
        }
        f32x4 c[4];
        #pragma unroll
        for (int t = 0; t < 4; t++) {
            c[t] = (f32x4){0.f, 0.f, 0.f, 0.f};
            #pragma unroll
            for (int k32 = 0; k32 < 4; k32++)
                c[t] = __builtin_amdgcn_mfma_f32_16x16x32_bf16(av[k32], bv[k32][t], c[t], 0, 0, 0);
        }
        #pragma unroll
        for (int t = 0; t < 4; t++) {
            #pragma unroll
            for (int j = 0; j < 4; j++) {
                int gr = r0 + kq * 4 + j;
                int col = t * 16 + m;
                if (gr < Nn) {
                    if (w < 2) {
                        outf[(size_t)gr * 64 + col] = c[t][j];
                    } else {
                        hproj[(size_t)gr * 128 + 2 * col + hsel] = f32_to_bf16_bits(c[t][j]);
                    }
                }
            }
        }
    }
}

// ---------------- K3a: per-chunk exclusive scan (chunks of 256) --------------
__global__ void k_scan_chunks(const int* __restrict__ count,
                              int* __restrict__ chunkscan,
                              int* __restrict__ chunktot, int n) {
    __shared__ int tmp[256];
    int t = threadIdx.x;
    int i = blockIdx.x * 256 + t;
    int v = (i < n) ? count[i] : 0;
    tmp[t] = v;
    __syncthreads();
    for (int o = 1; o < 256; o <<= 1) {
        int x = (t >= o) ? tmp[t - o] : 0;
        __syncthreads();
        tmp[t] += x;
        __syncthreads();
    }
    if (i < n) chunkscan[i] = tmp[t] - v;
    if (t == 255) chunktot[blockIdx.x] = tmp[t];
}

// ---------------- K3b: scan chunk totals (single block) ----------------------
__global__ void k_scan_tot(const int* __restrict__ tot, int* __restrict__ base, int nc) {
    __shared__ int tmp[1024];
    int t = threadIdx.x;
    int v = (t < nc) ? tot[t] : 0;
    tmp[t] = v;
    __syncthreads();
    for (int o = 1; o < 1024; o <<= 1) {
        int x = (t >= o) ? tmp[t - o] : 0;
        __syncthreads();
        tmp[t] += x;
        __syncthreads();
    }
    if (t < nc) base[t] = tmp[t] - v;
}

// ---------------- K3c: final offsets ----------------------------------------
__global__ void k_offsets(const int* __restrict__ chunkscan,
                          const int* __restrict__ chunkbase,
                          int* __restrict__ offsets, int Nn, int Ee) {
    int i = blockIdx.x * blockDim.x + threadIdx.x;
    if (i < Nn) offsets[i] = chunkscan[i] + chunkbase[i >> 8];
    if (i == 0) offsets[Nn] = Ee;
}

// ---------------- K4: fill CSR edge lists ------------------------------------
__global__ void k_fill(const int* __restrict__ dst,
                       const int* __restrict__ offsets,
                       int* __restrict__ cursor,
                       int* __restrict__ eids, int Ee) {
    int i = blockIdx.x * blockDim.x + threadIdx.x;
    int stride = gridDim.x * blockDim.x;
    for (; i < Ee; i += stride) {
        int d = dst[i];
        int p = atomicAdd(&cursor[d], 1);
        eids[offsets[d] + p] = i;
    }
}

// ---------------- K2: edge pass in CSR (dst-grouped) order -------------------
__launch_bounds__(256)
__global__ void k_edge(const float* __restrict__ efeats,
                       const int* __restrict__ src,
                       const int* __restrict__ dst,
                       const float* __restrict__ Wfij,   // [32][64]
                       const float* __restrict__ bias,   // [64]
                       const float* __restrict__ attn,   // [64]
                       const float* __restrict__ fni,
                       const float* __restrict__ fnj,
                       const int* __restrict__ eids,     // [E] CSR order
                       float* __restrict__ fout,         // [E,64] original order
                       float* __restrict__ exwsp,        // [E,4] CSR order
                       int* __restrict__ srcp,           // [E]   CSR order
                       int Ee) {
    int tid = threadIdx.x;
    int lane = tid & 63;
    int m = lane & 15;
    int kq = lane >> 4;
    bf16x8 bv[4];
    #pragma unroll
    for (int t = 0; t < 4; t++) {
        unsigned* bw = (unsigned*)&bv[t];
        #pragma unroll
        for (int i = 0; i < 4; i++) {
            float lo = Wfij[(kq * 8 + 2 * i) * HOE + t * 16 + m];
            float hi = Wfij[(kq * 8 + 2 * i + 1) * HOE + t * 16 + m];
            bw[i] = cvt_pk_bf16(lo, hi);
        }
    }
    float bb[4], aa[4];
    #pragma unroll
    for (int t = 0; t < 4; t++) { bb[t] = bias[t * 16 + m]; aa[t] = attn[t * 16 + m]; }

    int wid = (blockIdx.x * 256 + tid) >> 6;
    int nw = (gridDim.x * 256) >> 6;
    int ntiles = (Ee + 15) >> 4;
    for (int T = wid; T < ntiles; T += nw) {
        int i0 = T << 4;
        int ia = i0 + m;
        int ra = eids[(ia < Ee) ? ia : (Ee - 1)];
        const float* ap = &efeats[(size_t)ra * INE + kq * 8];
        f32x4 a0 = *(const f32x4*)ap;
        f32x4 a1 = *(const f32x4*)(ap + 4);
        int eq[4], sj[4], dj[4]; bool ok[4];
        #pragma unroll
        for (int j = 0; j < 4; j++) {
            int pos = i0 + kq * 4 + j;
            ok[j] = pos < Ee;
            int pc = ok[j] ? pos : (Ee - 1);
            eq[j] = eids[pc];
            sj[j] = src[eq[j]];
            dj[j] = dst[eq[j]];
        }
        float gni[4][4], gnj[4][4];
        #pragma unroll
        for (int j = 0; j < 4; j++) {
            const float* pi = &fni[(size_t)sj[j] * HOE + m];
            const float* pj = &fnj[(size_t)dj[j] * HOE + m];
            #pragma unroll
            for (int t = 0; t < 4; t++) {
                gni[j][t] = pi[t * 16];
                gnj[j][t] = pj[t * 16];
            }
        }
        bf16x8 av;
        {
            unsigned* aw = (unsigned*)&av;
            aw[0] = cvt_pk_bf16(a0[0], a0[1]);
            aw[1] = cvt_pk_bf16(a0[2], a0[3]);
            aw[2] = cvt_pk_bf16(a1[0], a1[1]);
            aw[3] = cvt_pk_bf16(a1[2], a1[3]);
        }
        f32x4 c[4];
        #pragma unroll
        for (int t = 0; t < 4; t++) {
            c[t] = __builtin_amdgcn_mfma_f32_16x16x32_bf16(av, bv[t], (f32x4){0.f,0.f,0.f,0.f}, 0, 0, 0);
        }
        #pragma unroll
        for (int j = 0; j < 4; j++) {
            int pos = i0 + kq * 4 + j;
            float pl[4];
            #pragma unroll
            for (int t = 0; t < 4; t++) {
                int col = t * 16 + m;
                float fv = c[t][j] + gni[j][t] + gnj[j][t] + bb[t];
                fv = fv > 0.f ? fv : 0.01f * fv;          // leaky relu
                if (ok[j]) fout[(size_t)eq[j] * HOE + col] = fv;
                pl[t] = rowsum16(fv * aa[t]);
            }
            if (ok[j] && m == 0) {
                float4 ex = make_float4(__expf(pl[0]), __expf(pl[1]),
                                        __expf(pl[2]), __expf(pl[3]));
                *(float4*)&exwsp[(size_t)pos * NH] = ex;
                srcp[pos] = sj[j];
            }
        }
    }
}

// ---------------- K5: node-centric softmax + aggregation ---------------------
// hproj2u: one dword per lane per edge (bf16 pair: col lane / col lane+64)
__launch_bounds__(256)
__global__ void k_node_out(const int* __restrict__ offsets,
                           const int* __restrict__ srcp,
                           const float* __restrict__ exwsp,   // [E,4] CSR order
                           const unsigned* __restrict__ hproj2u, // [N,64] bf16 pairs
                           float* __restrict__ hout,          // [N,128]
                           int Nn) {
    int lane = threadIdx.x & 63;
    int n = (blockIdx.x * 256 + threadIdx.x) >> 6;
    if (n >= Nn) return;
    int o0 = offsets[n], o1 = offsets[n + 1];
    int hi = lane >> 5;
    float s0 = 0.f, s1 = 0.f, s2 = 0.f, s3 = 0.f;
    float a0 = 0.f, a1 = 0.f;
    for (int i0 = o0; i0 < o1; i0 += 64) {
        int nb = min(64, o1 - i0);
        int vs = 0;
        if (lane < nb) vs = srcp[i0 + lane];               // coalesced
        for (int j0 = 0; j0 < nb; j0 += 4) {
            int cnt = nb - j0;
            float4 xx[4]; unsigned hp[4];
            #pragma unroll
            for (int u = 0; u < 4; u++) {
                int jj = j0 + ((u < cnt) ? u : cnt - 1);
                int s = __builtin_amdgcn_readlane(vs, jj);
                xx[u] = *(const float4*)&exwsp[(size_t)(i0 + jj) * NH];  // uniform addr
                hp[u] = hproj2u[(size_t)s * 64 + lane];
            }
            #pragma unroll
            for (int u = 0; u < 4; u++) {
                float4 x = xx[u];
                if (u >= cnt) x = make_float4(0.f, 0.f, 0.f, 0.f);
                s0 += x.x; s1 += x.y; s2 += x.z; s3 += x.w;
                float exl = (hi == 0) ? x.x : x.y;
                float exh = (hi == 0) ? x.z : x.w;
                float hlo = __uint_as_float((hp[u] & 0xffffu) << 16);
                float hhi = __uint_as_float(hp[u] & 0xffff0000u);
                a0 += hlo * exl;
                a1 += hhi * exh;
            }
        }
    }
    float r0 = s0 > 0.f ? 1.f / s0 : 0.f;
    float r1 = s1 > 0.f ? 1.f / s1 : 0.f;
    float r2 = s2 > 0.f ? 1.f / s2 : 0.f;
    float r3 = s3 > 0.f ? 1.f / s3 : 0.f;
    float rlo = (hi == 0) ? r0 : r1;
    float rhi = (hi == 0) ? r2 : r3;
    hout[(size_t)n * HON + lane] = a0 * rlo;
    hout[(size_t)n * HON + 64 + lane] = a1 * rhi;
}

// ---------------- launcher ----------------
extern "C" void kernel_launch(void* const* d_in, const int* in_sizes, int n_in,
                              void* d_out, int out_size, void* d_ws, size_t ws_size,
                              hipStream_t stream) {
    const float* n_feats = (const float*)d_in[0];
    const float* e_feats = (const float*)d_in[1];
    const int*   src     = (const int*)d_in[2];
    const int*   dst     = (const int*)d_in[3];
    const float* W_ni    = (const float*)d_in[4];
    const float* W_nj    = (const float*)d_in[5];
    const float* W_fij   = (const float*)d_in[6];
    const float* bias_e  = (const float*)d_in[7];
    const float* attn    = (const float*)d_in[8];
    const float* W_node  = (const float*)d_in[9];

    const int Nn = in_sizes[0] / INN;
    const int Ee = in_sizes[2];

    float* hout = (float*)d_out;                       // [N,128]
    float* fout = (float*)d_out + (size_t)Nn * HON;    // [E,64]

    char* ws = (char*)d_ws;
    size_t off = 0;
    auto alloc = [&](size_t bytes) {
        size_t o = off;
        off = (off + bytes + 255) & ~(size_t)255;
        return o;
    };
    size_t o_fni   = alloc((size_t)Nn * HOE * 4);
    size_t o_fnj   = alloc((size_t)Nn * HOE * 4);
    size_t o_hproj = alloc((size_t)Nn * HON * 2);      // bf16
    size_t o_exws  = alloc((size_t)Ee * NH * 4);
    size_t o_eids  = alloc((size_t)Ee * 4);
    size_t o_srcp  = alloc((size_t)Ee * 4);
    size_t o_cnt2  = alloc((size_t)2 * Nn * 4);        // count | cursor
    size_t o_offs  = alloc((size_t)(Nn + 1) * 4);
    size_t o_cscan = alloc((size_t)Nn * 4);
    size_t o_cbase = alloc((size_t)1024 * 4);
    (void)ws_size;

    float* fni   = (float*)(ws + o_fni);
    float* fnj   = (float*)(ws + o_fnj);
    unsigned short* hproj = (unsigned short*)(ws + o_hproj);
    float* exwsp = (float*)(ws + o_exws);
    int* eids    = (int*)(ws + o_eids);
    int* srcp    = (int*)(ws + o_srcp);
    int* cnt2    = (int*)(ws + o_cnt2);
    int* count   = cnt2;
    int* cursor  = cnt2 + Nn;
    int* offsets = (int*)(ws + o_offs);
    int* cscan   = (int*)(ws + o_cscan);
    int* cbase   = (int*)(ws + o_cbase);

    int nchunks = (Nn + 255) / 256;

    k_zero_i32<<<(2 * Nn + 255) / 256, 256, 0, stream>>>(cnt2, 2 * Nn);

    k_count<<<2048, 256, 0, stream>>>(dst, count, Ee);

    k_node_gemm<<<1024, 256, 0, stream>>>(
        n_feats, W_ni, W_nj, W_node, fni, fnj, hproj, Nn);

    k_scan_chunks<<<nchunks, 256, 0, stream>>>(count, cscan, cbase, Nn);
    k_scan_tot<<<1, 1024, 0, stream>>>(cbase, cbase, nchunks);
    k_offsets<<<(Nn + 255) / 256, 256, 0, stream>>>(cscan, cbase, offsets, Nn, Ee);

    k_fill<<<4096, 256, 0, stream>>>(dst, offsets, cursor, eids, Ee);

    k_edge<<<8192, 256, 0, stream>>>(
        e_feats, src, dst, W_fij, bias_e, attn, fni, fnj,
        eids, fout, exwsp, srcp, Ee);

    k_node_out<<<(Nn + 3) / 4, 256, 0, stream>>>(
        offsets, srcp, exwsp, (const unsigned*)hproj, hout, Nn);
}

// Round 11
// 571.877 us; speedup vs baseline: 1.1904x; 1.0627x over previous
//
#include <hip/hip_runtime.h>
#include <hip/hip_bf16.h>
#include <math.h>

#define NH 4      // heads
#define OE 16     // OUT_E
#define ON 32     // OUT_N
#define INN 128   // IN_N
#define INE 32    // IN_E
#define HOE 64    // NH*OE
#define HON 128   // NH*ON

typedef __attribute__((ext_vector_type(8))) short bf16x8;
typedef __attribute__((ext_vector_type(4))) float f32x4;

__device__ __forceinline__ unsigned cvt_pk_bf16(float lo, float hi) {
    unsigned r;
    asm volatile("v_cvt_pk_bf16_f32 %0, %1, %2" : "=v"(r) : "v"(lo), "v"(hi));
    return r;
}

__device__ __forceinline__ unsigned short f32_to_bf16_bits(float x) {
    unsigned u = __float_as_uint(x);
    unsigned r = (u + 0x7fff + ((u >> 16) & 1)) >> 16;   // RNE
    return (unsigned short)r;
}

__device__ __forceinline__ float bf16_lo(unsigned w) { return __uint_as_float(w << 16); }
__device__ __forceinline__ float bf16_hi(unsigned w) { return __uint_as_float(w & 0xffff0000u); }

// sum over each 16-lane row via DPP row_ror (VALU only, no DS pipe)
__device__ __forceinline__ float rowsum16(float v) {
    int x;
    x = __builtin_amdgcn_update_dpp(0, __float_as_int(v), 0x128, 0xf, 0xf, true); // ror:8
    v += __int_as_float(x);
    x = __builtin_amdgcn_update_dpp(0, __float_as_int(v), 0x124, 0xf, 0xf, true); // ror:4
    v += __int_as_float(x);
    x = __builtin_amdgcn_update_dpp(0, __float_as_int(v), 0x122, 0xf, 0xf, true); // ror:2
    v += __int_as_float(x);
    x = __builtin_amdgcn_update_dpp(0, __float_as_int(v), 0x121, 0xf, 0xf, true); // ror:1
    v += __int_as_float(x);
    return v;
}

// ---------------- K0: zero int32 buffer ----------------
__global__ void k_zero_i32(int* __restrict__ p, int n) {
    int i = blockIdx.x * blockDim.x + threadIdx.x;
    int stride = gridDim.x * blockDim.x;
    for (; i < n; i += stride) p[i] = 0;
}

// ---------------- K0b: degree count ----------------
__global__ void k_count(const int* __restrict__ dst, int* __restrict__ count, int Ee) {
    int i = blockIdx.x * blockDim.x + threadIdx.x;
    int stride = gridDim.x * blockDim.x;
    for (; i < Ee; i += stride) atomicAdd(&count[dst[i]], 1);
}

// ---------------- K1: fused node GEMM via MFMA -------------------------------
// wave 0->fni bf16 pairs, 1->fnj bf16 pairs, 2->hproj lo bf16, 3->hproj hi bf16
// fni/fnj layout: uint[row][32], word c = bf16(col c) | bf16(col c+32)<<16
// hproj layout: ushort[row][128], idx 2c = col c, 2c+1 = col c+64
__launch_bounds__(256)
__global__ void k_node_gemm(const float* __restrict__ nf,
                            const float* __restrict__ Wni,
                            const float* __restrict__ Wnj,
                            const float* __restrict__ Wnode,
                            unsigned* __restrict__ fni,
                            unsigned* __restrict__ fnj,
                            unsigned short* __restrict__ hproj,
                            int Nn) {
    int tid = threadIdx.x;
    int lane = tid & 63;
    int w = tid >> 6;
    int m = lane & 15;
    int kq = lane >> 4;
    const float* W; int wstride, wcoff;
    if (w == 0)      { W = Wni;   wstride = 64;  wcoff = 0;  }
    else if (w == 1) { W = Wnj;   wstride = 64;  wcoff = 0;  }
    else if (w == 2) { W = Wnode; wstride = 128; wcoff = 0;  }
    else             { W = Wnode; wstride = 128; wcoff = 64; }
    unsigned* outp = (w == 0) ? fni : fnj;
    int hsel = (w == 3);
    bf16x8 bv[4][4];
    #pragma unroll
    for (int k32 = 0; k32 < 4; k32++) {
        #pragma unroll
        for (int t = 0; t < 4; t++) {
            unsigned* bw = (unsigned*)&bv[k32][t];
            #pragma unroll
            for (int i = 0; i < 4; i++) {
                int k0 = k32 * 32 + kq * 8 + 2 * i;
                float lo = W[(size_t)k0 * wstride + wcoff + t * 16 + m];
                float hi = W[(size_t)(k0 + 1) * wstride + wcoff + t * 16 + m];
                bw[i] = cvt_pk_bf16(lo, hi);
            }
        }
    }
    int ngroups = (Nn + 15) >> 4;
    for (int g = blockIdx.x; g < ngroups; g += gridDim.x) {
        int r0 = g << 4;
        int ra = r0 + m; if (ra >= Nn) ra = Nn - 1;
        const float* ap = &nf[(size_t)ra * INN + kq * 8];
        bf16x8 av[4];
        #pragma unroll
        for (int k32 = 0; k32 < 4; k32++) {
            f32x4 a0 = *(const f32x4*)(ap + k32 * 32);
            f32x4 a1 = *(const f32x4*)(ap + k32 * 32 + 4);
            unsigned* aw = (unsigned*)&av[k32];
            aw[0] = cvt_pk_bf16(a0[0], a0[1]);
            aw[1] = cvt_pk_bf16(a0[2], a0[3]);
            aw[2] = cvt_pk_bf16(a1[0], a1[1]);
            aw[3] = cvt_pk_bf16(a1[2], a1[3]);
        }
        f32x4 c[4];
        #pragma unroll
        for (int t = 0; t < 4; t++) {
            c[t] = (f32x4){0.f, 0.f, 0.f, 0.f};
            #pragma unroll
            for (int k32 = 0; k32 < 4; k32++)
                c[t] = __builtin_amdgcn_mfma_f32_16x16x32_bf16(av[k32], bv[k32][t], c[t], 0, 0, 0);
        }
        #pragma unroll
        for (int j = 0; j < 4; j++) {
            int gr = r0 + kq * 4 + j;
            if (gr >= Nn) continue;
            if (w < 2) {
                // word m = (col m, col m+32); word m+16 = (col m+16, col m+48)
                outp[(size_t)gr * 32 + m]      = cvt_pk_bf16(c[0][j], c[2][j]);
                outp[(size_t)gr * 32 + m + 16] = cvt_pk_bf16(c[1][j], c[3][j]);
            } else {
                #pragma unroll
                for (int t = 0; t < 4; t++) {
                    int col = t * 16 + m;
                    hproj[(size_t)gr * 128 + 2 * col + hsel] = f32_to_bf16_bits(c[t][j]);
                }
            }
        }
    }
}

// ---------------- K3a: per-chunk exclusive scan (chunks of 256) --------------
__global__ void k_scan_chunks(const int* __restrict__ count,
                              int* __restrict__ chunkscan,
                              int* __restrict__ chunktot, int n) {
    __shared__ int tmp[256];
    int t = threadIdx.x;
    int i = blockIdx.x * 256 + t;
    int v = (i < n) ? count[i] : 0;
    tmp[t] = v;
    __syncthreads();
    for (int o = 1; o < 256; o <<= 1) {
        int x = (t >= o) ? tmp[t - o] : 0;
        __syncthreads();
        tmp[t] += x;
        __syncthreads();
    }
    if (i < n) chunkscan[i] = tmp[t] - v;
    if (t == 255) chunktot[blockIdx.x] = tmp[t];
}

// ---------------- K3b: scan chunk totals (single block) ----------------------
__global__ void k_scan_tot(const int* __restrict__ tot, int* __restrict__ base, int nc) {
    __shared__ int tmp[1024];
    int t = threadIdx.x;
    int v = (t < nc) ? tot[t] : 0;
    tmp[t] = v;
    __syncthreads();
    for (int o = 1; o < 1024; o <<= 1) {
        int x = (t >= o) ? tmp[t - o] : 0;
        __syncthreads();
        tmp[t] += x;
        __syncthreads();
    }
    if (t < nc) base[t] = tmp[t] - v;
}

// ---------------- K3c: final offsets ----------------------------------------
__global__ void k_offsets(const int* __restrict__ chunkscan,
                          const int* __restrict__ chunkbase,
                          int* __restrict__ offsets, int Nn, int Ee) {
    int i = blockIdx.x * blockDim.x + threadIdx.x;
    if (i < Nn) offsets[i] = chunkscan[i] + chunkbase[i >> 8];
    if (i == 0) offsets[Nn] = Ee;
}

// ---------------- K4: fill CSR edge lists ------------------------------------
__global__ void k_fill(const int* __restrict__ dst,
                       const int* __restrict__ offsets,
                       int* __restrict__ cursor,
                       int* __restrict__ eids, int Ee) {
    int i = blockIdx.x * blockDim.x + threadIdx.x;
    int stride = gridDim.x * blockDim.x;
    for (; i < Ee; i += stride) {
        int d = dst[i];
        int p = atomicAdd(&cursor[d], 1);
        eids[offsets[d] + p] = i;
    }
}

// ---------------- K2: edge pass in CSR (dst-grouped) order -------------------
__launch_bounds__(256)
__global__ void k_edge(const float* __restrict__ efeats,
                       const int* __restrict__ src,
                       const int* __restrict__ dst,
                       const float* __restrict__ Wfij,   // [32][64]
                       const float* __restrict__ bias,   // [64]
                       const float* __restrict__ attn,   // [64]
                       const unsigned* __restrict__ fni, // [N][32] bf16 pairs
                       const unsigned* __restrict__ fnj, // [N][32] bf16 pairs
                       const int* __restrict__ eids,     // [E] CSR order
                       float* __restrict__ fout,         // [E,64] original order
                       float* __restrict__ exwsp,        // [E,4] CSR order
                       int* __restrict__ srcp,           // [E]   CSR order
                       int Ee) {
    int tid = threadIdx.x;
    int lane = tid & 63;
    int m = lane & 15;
    int kq = lane >> 4;
    bf16x8 bv[4];
    #pragma unroll
    for (int t = 0; t < 4; t++) {
        unsigned* bw = (unsigned*)&bv[t];
        #pragma unroll
        for (int i = 0; i < 4; i++) {
            float lo = Wfij[(kq * 8 + 2 * i) * HOE + t * 16 + m];
            float hi = Wfij[(kq * 8 + 2 * i + 1) * HOE + t * 16 + m];
            bw[i] = cvt_pk_bf16(lo, hi);
        }
    }
    float bb[4], aa[4];
    #pragma unroll
    for (int t = 0; t < 4; t++) { bb[t] = bias[t * 16 + m]; aa[t] = attn[t * 16 + m]; }

    int wid = (blockIdx.x * 256 + tid) >> 6;
    int nw = (gridDim.x * 256) >> 6;
    int ntiles = (Ee + 15) >> 4;
    for (int T = wid; T < ntiles; T += nw) {
        int i0 = T << 4;
        int ia = i0 + m;
        int ra = eids[(ia < Ee) ? ia : (Ee - 1)];
        const float* ap = &efeats[(size_t)ra * INE + kq * 8];
        f32x4 a0 = *(const f32x4*)ap;
        f32x4 a1 = *(const f32x4*)(ap + 4);
        int eq[4], sj[4], dj[4]; bool ok[4];
        #pragma unroll
        for (int j = 0; j < 4; j++) {
            int pos = i0 + kq * 4 + j;
            ok[j] = pos < Ee;
            int pc = ok[j] ? pos : (Ee - 1);
            eq[j] = eids[pc];
            sj[j] = src[eq[j]];
            dj[j] = dst[eq[j]];
        }
        // gather clause: 2 words each of fni/fnj per j
        unsigned wi0[4], wi1[4], wj0[4], wj1[4];
        #pragma unroll
        for (int j = 0; j < 4; j++) {
            const unsigned* pi = &fni[(size_t)sj[j] * 32];
            const unsigned* pj = &fnj[(size_t)dj[j] * 32];
            wi0[j] = pi[m]; wi1[j] = pi[m + 16];
            wj0[j] = pj[m]; wj1[j] = pj[m + 16];
        }
        bf16x8 av;
        {
            unsigned* aw = (unsigned*)&av;
            aw[0] = cvt_pk_bf16(a0[0], a0[1]);
            aw[1] = cvt_pk_bf16(a0[2], a0[3]);
            aw[2] = cvt_pk_bf16(a1[0], a1[1]);
            aw[3] = cvt_pk_bf16(a1[2], a1[3]);
        }
        f32x4 c[4];
        #pragma unroll
        for (int t = 0; t < 4; t++) {
            c[t] = __builtin_amdgcn_mfma_f32_16x16x32_bf16(av, bv[t], (f32x4){0.f,0.f,0.f,0.f}, 0, 0, 0);
        }
        #pragma unroll
        for (int j = 0; j < 4; j++) {
            int pos = i0 + kq * 4 + j;
            // unpack gathers: t0=lo(w0), t1=lo(w1), t2=hi(w0), t3=hi(w1)
            float gni[4] = { bf16_lo(wi0[j]), bf16_lo(wi1[j]), bf16_hi(wi0[j]), bf16_hi(wi1[j]) };
            float gnj[4] = { bf16_lo(wj0[j]), bf16_lo(wj1[j]), bf16_hi(wj0[j]), bf16_hi(wj1[j]) };
            float pl[4];
            #pragma unroll
            for (int t = 0; t < 4; t++) {
                int col = t * 16 + m;
                float fv = c[t][j] + gni[t] + gnj[t] + bb[t];
                fv = fv > 0.f ? fv : 0.01f * fv;          // leaky relu
                if (ok[j]) fout[(size_t)eq[j] * HOE + col] = fv;
                pl[t] = rowsum16(fv * aa[t]);
            }
            if (ok[j] && m == 0) {
                float4 ex = make_float4(__expf(pl[0]), __expf(pl[1]),
                                        __expf(pl[2]), __expf(pl[3]));
                *(float4*)&exwsp[(size_t)pos * NH] = ex;
                srcp[pos] = sj[j];
            }
        }
    }
}

// ---------------- K5: node-centric softmax + aggregation ---------------------
__launch_bounds__(256)
__global__ void k_node_out(const int* __restrict__ offsets,
                           const int* __restrict__ srcp,
                           const float* __restrict__ exwsp,   // [E,4] CSR order
                           const unsigned* __restrict__ hproj2u, // [N,64] bf16 pairs
                           float* __restrict__ hout,          // [N,128]
                           int Nn) {
    int lane = threadIdx.x & 63;
    int n = (blockIdx.x * 256 + threadIdx.x) >> 6;
    if (n >= Nn) return;
    int o0 = offsets[n], o1 = offsets[n + 1];
    int hi = lane >> 5;
    float s0 = 0.f, s1 = 0.f, s2 = 0.f, s3 = 0.f;
    float a0 = 0.f, a1 = 0.f;
    for (int i0 = o0; i0 < o1; i0 += 64) {
        int nb = min(64, o1 - i0);
        int vs = 0;
        if (lane < nb) vs = srcp[i0 + lane];               // coalesced
        for (int j0 = 0; j0 < nb; j0 += 4) {
            int cnt = nb - j0;
            float4 xx[4]; unsigned hp[4];
            #pragma unroll
            for (int u = 0; u < 4; u++) {
                int jj = j0 + ((u < cnt) ? u : cnt - 1);
                int s = __builtin_amdgcn_readlane(vs, jj);
                xx[u] = *(const float4*)&exwsp[(size_t)(i0 + jj) * NH];  // uniform addr
                hp[u] = hproj2u[(size_t)s * 64 + lane];
            }
            #pragma unroll
            for (int u = 0; u < 4; u++) {
                float4 x = xx[u];
                if (u >= cnt) x = make_float4(0.f, 0.f, 0.f, 0.f);
                s0 += x.x; s1 += x.y; s2 += x.z; s3 += x.w;
                float exl = (hi == 0) ? x.x : x.y;
                float exh = (hi == 0) ? x.z : x.w;
                a0 += bf16_lo(hp[u]) * exl;
                a1 += bf16_hi(hp[u]) * exh;
            }
        }
    }
    float r0 = s0 > 0.f ? 1.f / s0 : 0.f;
    float r1 = s1 > 0.f ? 1.f / s1 : 0.f;
    float r2 = s2 > 0.f ? 1.f / s2 : 0.f;
    float r3 = s3 > 0.f ? 1.f / s3 : 0.f;
    float rlo = (hi == 0) ? r0 : r1;
    float rhi = (hi == 0) ? r2 : r3;
    hout[(size_t)n * HON + lane] = a0 * rlo;
    hout[(size_t)n * HON + 64 + lane] = a1 * rhi;
}

// ---------------- launcher ----------------
extern "C" void kernel_launch(void* const* d_in, const int* in_sizes, int n_in,
                              void* d_out, int out_size, void* d_ws, size_t ws_size,
                              hipStream_t stream) {
    const float* n_feats = (const float*)d_in[0];
    const float* e_feats = (const float*)d_in[1];
    const int*   src     = (const int*)d_in[2];
    const int*   dst     = (const int*)d_in[3];
    const float* W_ni    = (const float*)d_in[4];
    const float* W_nj    = (const float*)d_in[5];
    const float* W_fij   = (const float*)d_in[6];
    const float* bias_e  = (const float*)d_in[7];
    const float* attn    = (const float*)d_in[8];
    const float* W_node  = (const float*)d_in[9];

    const int Nn = in_sizes[0] / INN;
    const int Ee = in_sizes[2];

    float* hout = (float*)d_out;                       // [N,128]
    float* fout = (float*)d_out + (size_t)Nn * HON;    // [E,64]

    char* ws = (char*)d_ws;
    size_t off = 0;
    auto alloc = [&](size_t bytes) {
        size_t o = off;
        off = (off + bytes + 255) & ~(size_t)255;
        return o;
    };
    size_t o_fni   = alloc((size_t)Nn * 32 * 4);       // bf16 pairs
    size_t o_fnj   = alloc((size_t)Nn * 32 * 4);       // bf16 pairs
    size_t o_hproj = alloc((size_t)Nn * HON * 2);      // bf16
    size_t o_exws  = alloc((size_t)Ee * NH * 4);
    size_t o_eids  = alloc((size_t)Ee * 4);
    size_t o_srcp  = alloc((size_t)Ee * 4);
    size_t o_cnt2  = alloc((size_t)2 * Nn * 4);        // count | cursor
    size_t o_offs  = alloc((size_t)(Nn + 1) * 4);
    size_t o_cscan = alloc((size_t)Nn * 4);
    size_t o_cbase = alloc((size_t)1024 * 4);
    (void)ws_size;

    unsigned* fni = (unsigned*)(ws + o_fni);
    unsigned* fnj = (unsigned*)(ws + o_fnj);
    unsigned short* hproj = (unsigned short*)(ws + o_hproj);
    float* exwsp = (float*)(ws + o_exws);
    int* eids    = (int*)(ws + o_eids);
    int* srcp    = (int*)(ws + o_srcp);
    int* cnt2    = (int*)(ws + o_cnt2);
    int* count   = cnt2;
    int* cursor  = cnt2 + Nn;
    int* offsets = (int*)(ws + o_offs);
    int* cscan   = (int*)(ws + o_cscan);
    int* cbase   = (int*)(ws + o_cbase);

    int nchunks = (Nn + 255) / 256;

    k_zero_i32<<<(2 * Nn + 255) / 256, 256, 0, stream>>>(cnt2, 2 * Nn);

    k_count<<<2048, 256, 0, stream>>>(dst, count, Ee);

    k_node_gemm<<<1024, 256, 0, stream>>>(
        n_feats, W_ni, W_nj, W_node, fni, fnj, hproj, Nn);

    k_scan_chunks<<<nchunks, 256, 0, stream>>>(count, cscan, cbase, Nn);
    k_scan_tot<<<1, 1024, 0, stream>>>(cbase, cbase, nchunks);
    k_offsets<<<(Nn + 255) / 256, 256, 0, stream>>>(cscan, cbase, offsets, Nn, Ee);

    k_fill<<<4096, 256, 0, stream>>>(dst, offsets, cursor, eids, Ee);

    k_edge<<<8192, 256, 0, stream>>>(
        e_feats, src, dst, W_fij, bias_e, attn, fni, fnj,
        eids, fout, exwsp, srcp, Ee);

    k_node_out<<<(Nn + 3) / 4, 256, 0, stream>>>(
        offsets, srcp, exwsp, (const unsigned*)hproj, hout, Nn);
}

// Round 12
// 560.888 us; speedup vs baseline: 1.2138x; 1.0196x over previous
//
#include <hip/hip_runtime.h>
#include <hip/hip_bf16.h>
#include <math.h>

#define NH 4      // heads
#define OE 16     // OUT_E
#define ON 32     // OUT_N
#define INN 128   // IN_N
#define INE 32    // IN_E
#define HOE 64    // NH*OE
#define HON 128   // NH*ON

typedef __attribute__((ext_vector_type(8))) short bf16x8;
typedef __attribute__((ext_vector_type(4))) float f32x4;

__device__ __forceinline__ unsigned cvt_pk_bf16(float lo, float hi) {
    unsigned r;
    asm volatile("v_cvt_pk_bf16_f32 %0, %1, %2" : "=v"(r) : "v"(lo), "v"(hi));
    return r;
}

__device__ __forceinline__ unsigned short f32_to_bf16_bits(float x) {
    unsigned u = __float_as_uint(x);
    unsigned r = (u + 0x7fff + ((u >> 16) & 1)) >> 16;   // RNE
    return (unsigned short)r;
}

__device__ __forceinline__ float bf16_lo(unsigned w) { return __uint_as_float(w << 16); }
__device__ __forceinline__ float bf16_hi(unsigned w) { return __uint_as_float(w & 0xffff0000u); }

// sum over each 16-lane row via DPP row_ror (VALU only, no DS pipe)
__device__ __forceinline__ float rowsum16(float v) {
    int x;
    x = __builtin_amdgcn_update_dpp(0, __float_as_int(v), 0x128, 0xf, 0xf, true); // ror:8
    v += __int_as_float(x);
    x = __builtin_amdgcn_update_dpp(0, __float_as_int(v), 0x124, 0xf, 0xf, true); // ror:4
    v += __int_as_float(x);
    x = __builtin_amdgcn_update_dpp(0, __float_as_int(v), 0x122, 0xf, 0xf, true); // ror:2
    v += __int_as_float(x);
    x = __builtin_amdgcn_update_dpp(0, __float_as_int(v), 0x121, 0xf, 0xf, true); // ror:1
    v += __int_as_float(x);
    return v;
}

// ---------------- K0: zero int32 buffer ----------------
__global__ void k_zero_i32(int* __restrict__ p, int n) {
    int i = blockIdx.x * blockDim.x + threadIdx.x;
    int stride = gridDim.x * blockDim.x;
    for (; i < n; i += stride) p[i] = 0;
}

// ---------------- K0b: degree count ----------------
__global__ void k_count(const int* __restrict__ dst, int* __restrict__ count, int Ee) {
    int i = blockIdx.x * blockDim.x + threadIdx.x;
    int stride = gridDim.x * blockDim.x;
    for (; i < Ee; i += stride) atomicAdd(&count[dst[i]], 1);
}

// ---------------- K1: fused node GEMM via MFMA -------------------------------
// wave 0->fni bf16 pairs, 1->fnj bf16 pairs, 2->hproj lo bf16, 3->hproj hi bf16
__launch_bounds__(256)
__global__ void k_node_gemm(const float* __restrict__ nf,
                            const float* __restrict__ Wni,
                            const float* __restrict__ Wnj,
                            const float* __restrict__ Wnode,
                            unsigned* __restrict__ fni,
                            unsigned* __restrict__ fnj,
                            unsigned short* __restrict__ hproj,
                            int Nn) {
    int tid = threadIdx.x;
    int lane = tid & 63;
    int w = tid >> 6;
    int m = lane & 15;
    int kq = lane >> 4;
    const float* W; int wstride, wcoff;
    if (w == 0)      { W = Wni;   wstride = 64;  wcoff = 0;  }
    else if (w == 1) { W = Wnj;   wstride = 64;  wcoff = 0;  }
    else if (w == 2) { W = Wnode; wstride = 128; wcoff = 0;  }
    else             { W = Wnode; wstride = 128; wcoff = 64; }
    unsigned* outp = (w == 0) ? fni : fnj;
    int hsel = (w == 3);
    bf16x8 bv[4][4];
    #pragma unroll
    for (int k32 = 0; k32 < 4; k32++) {
        #pragma unroll
        for (int t = 0; t < 4; t++) {
            unsigned* bw = (unsigned*)&bv[k32][t];
            #pragma unroll
            for (int i = 0; i < 4; i++) {
                int k0 = k32 * 32 + kq * 8 + 2 * i;
                float lo = W[(size_t)k0 * wstride + wcoff + t * 16 + m];
                float hi = W[(size_t)(k0 + 1) * wstride + wcoff + t * 16 + m];
                bw[i] = cvt_pk_bf16(lo, hi);
            }
        }
    }
    int ngroups = (Nn + 15) >> 4;
    for (int g = blockIdx.x; g < ngroups; g += gridDim.x) {
        int r0 = g << 4;
        int ra = r0 + m; if (ra >= Nn) ra = Nn - 1;
        const float* ap = &nf[(size_t)ra * INN + kq * 8];
        bf16x8 av[4];
        #pragma unroll
        for (int k32 = 0; k32 < 4; k32++) {
            f32x4 a0 = *(const f32x4*)(ap + k32 * 32);
            f32x4 a1 = *(const f32x4*)(ap + k32 * 32 + 4);
            unsigned* aw = (unsigned*)&av[k32];
            aw[0] = cvt_pk_bf16(a0[0], a0[1]);
            aw[1] = cvt_pk_bf16(a0[2], a0[3]);
            aw[2] = cvt_pk_bf16(a1[0], a1[1]);
            aw[3] = cvt_pk_bf16(a1[2], a1[3]);
        }
        f32x4 c[4];
        #pragma unroll
        for (int t = 0; t < 4; t++) {
            c[t] = (f32x4){0.f, 0.f, 0.f, 0.f};
            #pragma unroll
            for (int k32 = 0; k32 < 4; k32++)
                c[t] = __builtin_amdgcn_mfma_f32_16x16x32_bf16(av[k32], bv[k32][t], c[t], 0, 0, 0);
        }
        #pragma unroll
        for (int j = 0; j < 4; j++) {
            int gr = r0 + kq * 4 + j;
            if (gr >= Nn) continue;
            if (w < 2) {
                outp[(size_t)gr * 32 + m]      = cvt_pk_bf16(c[0][j], c[2][j]);
                outp[(size_t)gr * 32 + m + 16] = cvt_pk_bf16(c[1][j], c[3][j]);
            } else {
                #pragma unroll
                for (int t = 0; t < 4; t++) {
                    int col = t * 16 + m;
                    hproj[(size_t)gr * 128 + 2 * col + hsel] = f32_to_bf16_bits(c[t][j]);
                }
            }
        }
    }
}

// ---------------- K3a: per-chunk exclusive scan (chunks of 256) --------------
__global__ void k_scan_chunks(const int* __restrict__ count,
                              int* __restrict__ chunkscan,
                              int* __restrict__ chunktot, int n) {
    __shared__ int tmp[256];
    int t = threadIdx.x;
    int i = blockIdx.x * 256 + t;
    int v = (i < n) ? count[i] : 0;
    tmp[t] = v;
    __syncthreads();
    for (int o = 1; o < 256; o <<= 1) {
        int x = (t >= o) ? tmp[t - o] : 0;
        __syncthreads();
        tmp[t] += x;
        __syncthreads();
    }
    if (i < n) chunkscan[i] = tmp[t] - v;
    if (t == 255) chunktot[blockIdx.x] = tmp[t];
}

// ---------------- K3b: scan chunk totals (single block) ----------------------
__global__ void k_scan_tot(const int* __restrict__ tot, int* __restrict__ base, int nc) {
    __shared__ int tmp[1024];
    int t = threadIdx.x;
    int v = (t < nc) ? tot[t] : 0;
    tmp[t] = v;
    __syncthreads();
    for (int o = 1; o < 1024; o <<= 1) {
        int x = (t >= o) ? tmp[t - o] : 0;
        __syncthreads();
        tmp[t] += x;
        __syncthreads();
    }
    if (t < nc) base[t] = tmp[t] - v;
}

// ---------------- K3c: final offsets ----------------------------------------
__global__ void k_offsets(const int* __restrict__ chunkscan,
                          const int* __restrict__ chunkbase,
                          int* __restrict__ offsets, int Nn, int Ee) {
    int i = blockIdx.x * blockDim.x + threadIdx.x;
    if (i < Nn) offsets[i] = chunkscan[i] + chunkbase[i >> 8];
    if (i == 0) offsets[Nn] = Ee;
}

// ---------------- K4: fill CSR edge lists ------------------------------------
__global__ void k_fill(const int* __restrict__ dst,
                       const int* __restrict__ offsets,
                       int* __restrict__ cursor,
                       int* __restrict__ eids, int Ee) {
    int i = blockIdx.x * blockDim.x + threadIdx.x;
    int stride = gridDim.x * blockDim.x;
    for (; i < Ee; i += stride) {
        int d = dst[i];
        int p = atomicAdd(&cursor[d], 1);
        eids[offsets[d] + p] = i;
    }
}

// ---------------- K2: edge pass in CSR (dst-grouped) order -------------------
__launch_bounds__(256)
__global__ void k_edge(const float* __restrict__ efeats,
                       const int* __restrict__ src,
                       const int* __restrict__ dst,
                       const float* __restrict__ Wfij,   // [32][64]
                       const float* __restrict__ bias,   // [64]
                       const float* __restrict__ attn,   // [64]
                       const unsigned* __restrict__ fni, // [N][32] bf16 pairs
                       const unsigned* __restrict__ fnj, // [N][32] bf16 pairs
                       const int* __restrict__ eids,     // [E] CSR order
                       float* __restrict__ fout,         // [E,64] original order
                       float* __restrict__ exwsp,        // [E,4] CSR order
                       int* __restrict__ srcp,           // [E]   CSR order
                       int Ee) {
    int tid = threadIdx.x;
    int lane = tid & 63;
    int m = lane & 15;
    int kq = lane >> 4;
    bf16x8 bv[4];
    #pragma unroll
    for (int t = 0; t < 4; t++) {
        unsigned* bw = (unsigned*)&bv[t];
        #pragma unroll
        for (int i = 0; i < 4; i++) {
            float lo = Wfij[(kq * 8 + 2 * i) * HOE + t * 16 + m];
            float hi = Wfij[(kq * 8 + 2 * i + 1) * HOE + t * 16 + m];
            bw[i] = cvt_pk_bf16(lo, hi);
        }
    }
    float bb[4], aa[4];
    #pragma unroll
    for (int t = 0; t < 4; t++) { bb[t] = bias[t * 16 + m]; aa[t] = attn[t * 16 + m]; }

    int wid = (blockIdx.x * 256 + tid) >> 6;
    int nw = (gridDim.x * 256) >> 6;
    int ntiles = (Ee + 15) >> 4;
    for (int T = wid; T < ntiles; T += nw) {
        int i0 = T << 4;
        int ia = i0 + m;
        int ra = eids[(ia < Ee) ? ia : (Ee - 1)];
        const float* ap = &efeats[(size_t)ra * INE + kq * 8];
        f32x4 a0 = __builtin_nontemporal_load((const f32x4*)ap);       // read-once stream
        f32x4 a1 = __builtin_nontemporal_load((const f32x4*)(ap + 4)); // keep out of L2/L3
        int eq[4], sj[4], dj[4]; bool ok[4];
        #pragma unroll
        for (int j = 0; j < 4; j++) {
            int pos = i0 + kq * 4 + j;
            ok[j] = pos < Ee;
            int pc = ok[j] ? pos : (Ee - 1);
            eq[j] = eids[pc];
            sj[j] = src[eq[j]];
            dj[j] = dst[eq[j]];
        }
        // gather clause: 2 words each of fni/fnj per j
        unsigned wi0[4], wi1[4], wj0[4], wj1[4];
        #pragma unroll
        for (int j = 0; j < 4; j++) {
            const unsigned* pi = &fni[(size_t)sj[j] * 32];
            const unsigned* pj = &fnj[(size_t)dj[j] * 32];
            wi0[j] = pi[m]; wi1[j] = pi[m + 16];
            wj0[j] = pj[m]; wj1[j] = pj[m + 16];
        }
        bf16x8 av;
        {
            unsigned* aw = (unsigned*)&av;
            aw[0] = cvt_pk_bf16(a0[0], a0[1]);
            aw[1] = cvt_pk_bf16(a0[2], a0[3]);
            aw[2] = cvt_pk_bf16(a1[0], a1[1]);
            aw[3] = cvt_pk_bf16(a1[2], a1[3]);
        }
        f32x4 c[4];
        #pragma unroll
        for (int t = 0; t < 4; t++) {
            c[t] = __builtin_amdgcn_mfma_f32_16x16x32_bf16(av, bv[t], (f32x4){0.f,0.f,0.f,0.f}, 0, 0, 0);
        }
        #pragma unroll
        for (int j = 0; j < 4; j++) {
            int pos = i0 + kq * 4 + j;
            float gni[4] = { bf16_lo(wi0[j]), bf16_lo(wi1[j]), bf16_hi(wi0[j]), bf16_hi(wi1[j]) };
            float gnj[4] = { bf16_lo(wj0[j]), bf16_lo(wj1[j]), bf16_hi(wj0[j]), bf16_hi(wj1[j]) };
            float pl[4];
            #pragma unroll
            for (int t = 0; t < 4; t++) {
                int col = t * 16 + m;
                float fv = c[t][j] + gni[t] + gnj[t] + bb[t];
                fv = fv > 0.f ? fv : 0.01f * fv;          // leaky relu
                if (ok[j]) fout[(size_t)eq[j] * HOE + col] = fv;
                pl[t] = rowsum16(fv * aa[t]);
            }
            if (ok[j] && m == 0) {
                float4 ex = make_float4(__expf(pl[0]), __expf(pl[1]),
                                        __expf(pl[2]), __expf(pl[3]));
                *(float4*)&exwsp[(size_t)pos * NH] = ex;
                srcp[pos] = sj[j];
            }
        }
    }
}

// ---------------- K5: node-centric softmax + aggregation ---------------------
__launch_bounds__(256)
__global__ void k_node_out(const int* __restrict__ offsets,
                           const int* __restrict__ srcp,
                           const float* __restrict__ exwsp,   // [E,4] CSR order
                           const unsigned* __restrict__ hproj2u, // [N,64] bf16 pairs
                           float* __restrict__ hout,          // [N,128]
                           int Nn) {
    int lane = threadIdx.x & 63;
    int n = (blockIdx.x * 256 + threadIdx.x) >> 6;
    if (n >= Nn) return;
    // wave-uniform bounds -> SGPRs (enables scalar loads for uniform addrs)
    int o0 = __builtin_amdgcn_readfirstlane(offsets[n]);
    int o1 = __builtin_amdgcn_readfirstlane(offsets[n + 1]);
    int hi = lane >> 5;
    float s0 = 0.f, s1 = 0.f, s2 = 0.f, s3 = 0.f;
    float a0 = 0.f, a1 = 0.f;
    for (int i0 = o0; i0 < o1; i0 += 64) {
        int nb = min(64, o1 - i0);
        int vs = 0;
        if (lane < nb) vs = srcp[i0 + lane];               // coalesced
        for (int j0 = 0; j0 < nb; j0 += 8) {
            int cnt = nb - j0;
            float4 xx[8]; unsigned hp[8];
            #pragma unroll
            for (int u = 0; u < 8; u++) {
                int jj = j0 + ((u < cnt) ? u : cnt - 1);
                int s = __builtin_amdgcn_readlane(vs, jj);
                xx[u] = *(const float4*)&exwsp[(size_t)(i0 + jj) * NH];  // uniform addr
                hp[u] = hproj2u[(size_t)s * 64 + lane];
            }
            #pragma unroll
            for (int u = 0; u < 8; u++) {
                float4 x = xx[u];
                if (u >= cnt) x = make_float4(0.f, 0.f, 0.f, 0.f);
                s0 += x.x; s1 += x.y; s2 += x.z; s3 += x.w;
                float exl = (hi == 0) ? x.x : x.y;
                float exh = (hi == 0) ? x.z : x.w;
                a0 += bf16_lo(hp[u]) * exl;
                a1 += bf16_hi(hp[u]) * exh;
            }
        }
    }
    float r0 = s0 > 0.f ? 1.f / s0 : 0.f;
    float r1 = s1 > 0.f ? 1.f / s1 : 0.f;
    float r2 = s2 > 0.f ? 1.f / s2 : 0.f;
    float r3 = s3 > 0.f ? 1.f / s3 : 0.f;
    float rlo = (hi == 0) ? r0 : r1;
    float rhi = (hi == 0) ? r2 : r3;
    hout[(size_t)n * HON + lane] = a0 * rlo;
    hout[(size_t)n * HON + 64 + lane] = a1 * rhi;
}

// ---------------- launcher ----------------
extern "C" void kernel_launch(void* const* d_in, const int* in_sizes, int n_in,
                              void* d_out, int out_size, void* d_ws, size_t ws_size,
                              hipStream_t stream) {
    const float* n_feats = (const float*)d_in[0];
    const float* e_feats = (const float*)d_in[1];
    const int*   src     = (const int*)d_in[2];
    const int*   dst     = (const int*)d_in[3];
    const float* W_ni    = (const float*)d_in[4];
    const float* W_nj    = (const float*)d_in[5];
    const float* W_fij   = (const float*)d_in[6];
    const float* bias_e  = (const float*)d_in[7];
    const float* attn    = (const float*)d_in[8];
    const float* W_node  = (const float*)d_in[9];

    const int Nn = in_sizes[0] / INN;
    const int Ee = in_sizes[2];

    float* hout = (float*)d_out;                       // [N,128]
    float* fout = (float*)d_out + (size_t)Nn * HON;    // [E,64]

    char* ws = (char*)d_ws;
    size_t off = 0;
    auto alloc = [&](size_t bytes) {
        size_t o = off;
        off = (off + bytes + 255) & ~(size_t)255;
        return o;
    };
    size_t o_fni   = alloc((size_t)Nn * 32 * 4);       // bf16 pairs
    size_t o_fnj   = alloc((size_t)Nn * 32 * 4);       // bf16 pairs
    size_t o_hproj = alloc((size_t)Nn * HON * 2);      // bf16
    size_t o_exws  = alloc((size_t)Ee * NH * 4);
    size_t o_eids  = alloc((size_t)Ee * 4);
    size_t o_srcp  = alloc((size_t)Ee * 4);
    size_t o_cnt2  = alloc((size_t)2 * Nn * 4);        // count | cursor
    size_t o_offs  = alloc((size_t)(Nn + 1) * 4);
    size_t o_cscan = alloc((size_t)Nn * 4);
    size_t o_cbase = alloc((size_t)1024 * 4);
    (void)ws_size;

    unsigned* fni = (unsigned*)(ws + o_fni);
    unsigned* fnj = (unsigned*)(ws + o_fnj);
    unsigned short* hproj = (unsigned short*)(ws + o_hproj);
    float* exwsp = (float*)(ws + o_exws);
    int* eids    = (int*)(ws + o_eids);
    int* srcp    = (int*)(ws + o_srcp);
    int* cnt2    = (int*)(ws + o_cnt2);
    int* count   = cnt2;
    int* cursor  = cnt2 + Nn;
    int* offsets = (int*)(ws + o_offs);
    int* cscan   = (int*)(ws + o_cscan);
    int* cbase   = (int*)(ws + o_cbase);

    int nchunks = (Nn + 255) / 256;

    k_zero_i32<<<(2 * Nn + 255) / 256, 256, 0, stream>>>(cnt2, 2 * Nn);

    k_count<<<2048, 256, 0, stream>>>(dst, count, Ee);

    k_node_gemm<<<1024, 256, 0, stream>>>(
        n_feats, W_ni, W_nj, W_node, fni, fnj, hproj, Nn);

    k_scan_chunks<<<nchunks, 256, 0, stream>>>(count, cscan, cbase, Nn);
    k_scan_tot<<<1, 1024, 0, stream>>>(cbase, cbase, nchunks);
    k_offsets<<<(Nn + 255) / 256, 256, 0, stream>>>(cscan, cbase, offsets, Nn, Ee);

    k_fill<<<4096, 256, 0, stream>>>(dst, offsets, cursor, eids, Ee);

    k_edge<<<8192, 256, 0, stream>>>(
        e_feats, src, dst, W_fij, bias_e, attn, fni, fnj,
        eids, fout, exwsp, srcp, Ee);

    k_node_out<<<(Nn + 3) / 4, 256, 0, stream>>>(
        offsets, srcp, exwsp, (const unsigned*)hproj, hout, Nn);
}